// Round 8
// baseline (717.678 us; speedup 1.0000x reference)
//
#include <hip/hip_runtime.h>

#define E_N   8
#define IN_N  4096
#define OUT_N 4096
#define T_N   8192

#define BM 256
#define BN 256
#define NT_K 64            // number of 64-wide K-tiles
#define NTHREADS 512
#define MAXMT 64           // max m-tiles (actual <= 40)

typedef unsigned short u16;
typedef __bf16 bf16_t;
typedef bf16_t bf16x8 __attribute__((ext_vector_type(8)));
typedef u16    u16x8  __attribute__((ext_vector_type(8)));
typedef float  f32x4  __attribute__((ext_vector_type(4)));

// async global->LDS, 16B per lane (dest must be lane-linear: base + lane*16)
#define GLOAD16(gsrc, ldst) \
    __builtin_amdgcn_global_load_lds( \
        (const __attribute__((address_space(1))) unsigned int*)(gsrc), \
        (__attribute__((address_space(3))) unsigned int*)(ldst), 16, 0, 0)

// ---- device-global scratch (ws_size unknown -> module globals) ----
__device__ int g_cnt[E_N];
__device__ int g_base[E_N];
__device__ int g_ids[T_N];
__device__ int g_meta_wide;                       // 1 if meta widened int16->int32
__device__ int g_mt_e[MAXMT];                     // m-tile -> expert
__device__ int g_mt_m0[MAXMT];                    // m-tile -> row offset within expert
__device__ int g_nmt;                             // number of active m-tiles
// W stored as the LDS-image of each (e,kt) slab [256 rows][8 chunks of 16B],
// chunk h of row o at chunk index o*8 + (h ^ (o&7))  (T2 swizzle).
__device__ u16 g_W[(long)E_N * OUT_N * IN_N];     // 268 MB dense bf16
__device__ u16 g_xb[(long)T_N * IN_N];            // 67 MB sorted bf16 tokens

__device__ __forceinline__ u16 f2bf(float f) {
    unsigned u = __builtin_bit_cast(unsigned, f);
    u += 0x7FFFu + ((u >> 16) & 1u);              // round-to-nearest-even
    return (u16)(u >> 16);
}

// ---------------- kernel 1: bucket tokens + meta-layout probe + tile map ----------------
__global__ void sort_tokens(const int* __restrict__ idx, const u16* __restrict__ meta16) {
    __shared__ int cnt[E_N], off[E_N];
    __shared__ int probe;
    const int tid = threadIdx.x;
    const int lane = tid & 63;
    if (tid == 0) probe = 0;
    if (tid < E_N) cnt[tid] = 0;
    __syncthreads();
    if (tid < 64) {
        unsigned v = meta16[2 * (tid * 131072) + 1];   // int32-widened meta -> odd u16 halves all 0
        if (v) atomicOr(&probe, 1);
    }
    for (int t0 = tid - lane; t0 < T_N; t0 += blockDim.x) {
        const int t = t0 + lane;
        const int my = idx[t] & 7;
        #pragma unroll
        for (int e = 0; e < E_N; ++e) {
            unsigned long long m = __ballot(my == e);
            if (lane == 0 && m) atomicAdd(&cnt[e], __popcll(m));
        }
    }
    __syncthreads();
    if (tid == 0) {
        int s = 0;
        for (int e = 0; e < E_N; ++e) { g_cnt[e] = cnt[e]; g_base[e] = s; off[e] = s; s += cnt[e]; }
        g_meta_wide = (probe == 0) ? 1 : 0;
        int n = 0;
        for (int e = 0; e < E_N; ++e)
            for (int m0 = 0; m0 < cnt[e] && n < MAXMT; m0 += BM) { g_mt_e[n] = e; g_mt_m0[n] = m0; ++n; }
        g_nmt = n;
    }
    __syncthreads();
    for (int t0 = tid - lane; t0 < T_N; t0 += blockDim.x) {
        const int t = t0 + lane;
        const int my = idx[t] & 7;
        #pragma unroll
        for (int e = 0; e < E_N; ++e) {
            unsigned long long m = __ballot(my == e);
            if (my == e) {
                int below = __popcll(m & ((1ull << lane) - 1ull));
                int basep = 0;
                if (below == 0) basep = atomicAdd(&off[e], __popcll(m));
                int src = __ffsll((long long)m) - 1;
                basep = __shfl(basep, src);
                int p = basep + below;
                if (p >= 0 && p < T_N) g_ids[p] = t;
            }
        }
    }
}

// ---------------- kernel 2: gather + convert x (f32) -> sorted bf16 rows ----------------
__global__ __launch_bounds__(256, 4)
void xb_convert(const float* __restrict__ x) {
    const int p = blockIdx.x;
    int tok = g_ids[p];
    if ((unsigned)tok >= (unsigned)T_N) tok = 0;
    const float* src = x + (long)tok * IN_N;
    u16* dst = g_xb + (long)p * IN_N;
    const int tid = threadIdx.x;
    float va[16];
    #pragma unroll
    for (int c4 = 0; c4 < 4; ++c4) {
        float4 v = *reinterpret_cast<const float4*>(src + tid * 16 + c4 * 4);
        va[c4 * 4 + 0] = v.x; va[c4 * 4 + 1] = v.y; va[c4 * 4 + 2] = v.z; va[c4 * 4 + 3] = v.w;
    }
    unsigned wp[8];
    #pragma unroll
    for (int p8 = 0; p8 < 8; ++p8)
        wp[p8] = (unsigned)f2bf(va[2 * p8]) | ((unsigned)f2bf(va[2 * p8 + 1]) << 16);
    *reinterpret_cast<int4*>(dst + tid * 16)     = make_int4((int)wp[0], (int)wp[1], (int)wp[2], (int)wp[3]);
    *reinterpret_cast<int4*>(dst + tid * 16 + 8) = make_int4((int)wp[4], (int)wp[5], (int)wp[6], (int)wp[7]);
}

// ---------------- kernel 3: decode 2:4 int4 -> dense bf16 W, swizzled k-tiled layout ----------------
__global__ __launch_bounds__(256, 4)
void decode_w(const int* __restrict__ qw, const void* __restrict__ meta) {
    const int e   = blockIdx.z;
    const int kt0 = blockIdx.y * 4;
    const int o   = blockIdx.x * 256 + threadIdx.x;
    const bool mwide = (g_meta_wide != 0);
    unsigned mws[16];
    if (mwide) {
        const int* mp = (const int*)meta + ((long)e * OUT_N + o) * (IN_N / 16) + kt0 * 4;
        #pragma unroll
        for (int i = 0; i < 16; ++i) mws[i] = (unsigned)mp[i] & 0xFFFFu;
    } else {
        const u16* mp = (const u16*)meta + ((long)e * OUT_N + o) * (IN_N / 16) + kt0 * 4;
        #pragma unroll
        for (int i = 0; i < 16; ++i) mws[i] = mp[i];
    }
    const unsigned sh = (o & 7) << 2;
    const int osw = o & 7;
    #pragma unroll
    for (int ki = 0; ki < 4; ++ki) {
        const int kt = kt0 + ki;
        unsigned wp[32];
        #pragma unroll
        for (int gi = 0; gi < 4; ++gi) {
            const int g = kt * 4 + gi;
            const unsigned mw = mws[ki * 4 + gi];
            const int* qp = qw + ((e * (IN_N / 32) + (g >> 1)) << 13) + (o >> 3) + ((g & 1) << 12);
            int d[16];
            #pragma unroll
            for (int p = 0; p < 16; ++p) d[p] = 0;
            #pragma unroll
            for (int grp = 0; grp < 4; ++grp) {
                const unsigned w0 = (unsigned)qp[(2 * grp) * 512];
                const unsigned w1 = (unsigned)qp[(2 * grp + 1) * 512];
                const int v0 = (int)((w0 >> sh) & 0xF) - 8;
                const int v1 = (int)((w1 >> sh) & 0xF) - 8;
                const int s0 = (mw >> (4 * grp)) & 3;
                const int s1 = (mw >> (4 * grp + 2)) & 3;
                #pragma unroll
                for (int q = 0; q < 4; ++q) {
                    int t0 = (s0 == q) ? v0 : 0;
                    int t1 = (s1 == q) ? v1 : 0;
                    d[grp * 4 + q] = t0 + t1;     // collisions sum, matching .at[].add
                }
            }
            #pragma unroll
            for (int p = 0; p < 8; ++p) {
                unsigned lo = __builtin_bit_cast(unsigned, (float)d[2 * p])     >> 16;  // exact, |d|<=30
                unsigned hi = __builtin_bit_cast(unsigned, (float)d[2 * p + 1]) >> 16;
                wp[gi * 8 + p] = lo | (hi << 16);
            }
        }
        u16* wr = g_W + ((long)(e * 64 + kt) * OUT_N + o) * 64;
        #pragma unroll
        for (int h = 0; h < 8; ++h)
            *reinterpret_cast<int4*>(wr + (h ^ osw) * 8) =
                make_int4((int)wp[h * 4], (int)wp[h * 4 + 1], (int)wp[h * 4 + 2], (int)wp[h * 4 + 3]);
    }
}

// ---------------- kernel 4: grouped bf16 GEMM, 256x256 8-phase, deep-counted vmcnt ----------------
__global__ __launch_bounds__(NTHREADS, 2)
void moe_gemm(const float* __restrict__ scales, float* __restrict__ y) {
    // compact flattened grid 640 = 8 XCD chunks x 80 (5 m-tiles x 16 n-tiles per chunk)
    const int blk = blockIdx.x;
    const int swz = (blk & 7) * 80 + (blk >> 3);     // bijective on [0,640)
    const int mIdx = swz >> 4, nIdx = swz & 15;
    if (mIdx >= g_nmt) return;
    const int e  = g_mt_e[mIdx];
    const int m0 = g_mt_m0[mIdx];
    const int n0 = nIdx * BN;
    int cnt = g_cnt[e];
    if (cnt < 0) cnt = 0;
    if (cnt > T_N) cnt = T_N;
    if (m0 >= cnt) return;
    int base = g_base[e];
    if (base < 0) base = 0;
    if (base > T_N - cnt) base = T_N - cnt;

    __shared__ __align__(16) u16 As[2 * BM * 64];   // 64 KiB, swizzled image
    __shared__ __align__(16) u16 Bs[2 * BN * 64];   // 64 KiB

    const int tid  = threadIdx.x;
    const int lane = tid & 63;
    const int wid  = tid >> 6;
    const int wm   = wid >> 2;     // 0..1
    const int wn   = wid & 3;      // 0..3

    // ---- staging precompute (per-lane swizzled global source, linear LDS dest) ----
    const int r_loc = tid >> 3;
    const int h_a   = (tid & 7) ^ (r_loc & 7);
    const u16* asrc[4];
    #pragma unroll
    for (int q = 0; q < 4; ++q) {                  // row = m0 + q*64 + r_loc
        long grow = (long)base + m0 + q * 64 + r_loc;
        if (grow > T_N - 1) grow = T_N - 1;        // tail rows: dup data, masked at store
        asrc[q] = g_xb + grow * IN_N + h_a * 8;
    }
    const u16* bsrc = g_W + ((long)e * NT_K * OUT_N + n0) * 64 + (long)tid * 8;

#define STAGE_A4(B_, KT_) do { \
    GLOAD16(asrc[0] + (KT_) * 64, &As[(B_)*16384 + tid * 8]); \
    GLOAD16(asrc[1] + (KT_) * 64, &As[(B_)*16384 + (512 + tid) * 8]); \
    GLOAD16(asrc[2] + (KT_) * 64, &As[(B_)*16384 + (1024 + tid) * 8]); \
    GLOAD16(asrc[3] + (KT_) * 64, &As[(B_)*16384 + (1536 + tid) * 8]); \
} while (0)
#define STAGE_B4(B_, KT_) do { \
    const u16* s_ = bsrc + (long)(KT_) * (OUT_N * 64); \
    GLOAD16(s_,         &Bs[(B_)*16384 + tid * 8]); \
    GLOAD16(s_ + 4096,  &Bs[(B_)*16384 + (512 + tid) * 8]); \
    GLOAD16(s_ + 8192,  &Bs[(B_)*16384 + (1024 + tid) * 8]); \
    GLOAD16(s_ + 12288, &Bs[(B_)*16384 + (1536 + tid) * 8]); \
} while (0)

    // ---- MFMA-read precompute ----
    const int l15   = lane & 15;
    const int aoff0 = ((((lane >> 4))     ^ (lane & 7)) << 3);   // ks=0
    const int aoff1 = (((4 + (lane >> 4)) ^ (lane & 7)) << 3);   // ks=1
    const int arow0 = (wm * 128 + l15) * 64;
    const int brow0 = (wn * 64  + l15) * 64;

#define LD8(P_) __builtin_bit_cast(bf16x8, *reinterpret_cast<const u16x8*>(P_))
#define VM8 asm volatile("s_waitcnt vmcnt(8)" ::: "memory")
#define PH_NOP ((void)0)

    f32x4 acc[8][4];
    #pragma unroll
    for (int i = 0; i < 8; ++i)
        #pragma unroll
        for (int j = 0; j < 4; ++j) acc[i][j] = (f32x4){0.f, 0.f, 0.f, 0.f};

    bf16x8 aR[4][2];       // A frags for current qm
    bf16x8 bR[2][2][2];    // B frags for BOTH qn (B LDS region free after phase 2)

// one phase: {ds_read subtile | stage | barrier | lgkmcnt(0) | setprio(1) 16xMFMA setprio(0) | tail | barrier}
#define PH(B_, QM_, QN_, RDA_, RDB_, STAGE_STMT, TAIL_STMT) do { \
    if (RDA_) { _Pragma("unroll") for (int mf = 0; mf < 4; ++mf) { \
        const u16* p_ = &As[(B_)*16384 + arow0 + (QM_)*4096 + mf*1024]; \
        aR[mf][0] = LD8(p_ + aoff0); aR[mf][1] = LD8(p_ + aoff1); } } \
    if (RDB_) { _Pragma("unroll") for (int nf = 0; nf < 2; ++nf) { \
        const u16* p_ = &Bs[(B_)*16384 + brow0 + (QN_)*2048 + nf*1024]; \
        bR[QN_][nf][0] = LD8(p_ + aoff0); bR[QN_][nf][1] = LD8(p_ + aoff1); } } \
    STAGE_STMT; \
    __builtin_amdgcn_s_barrier(); \
    asm volatile("s_waitcnt lgkmcnt(0)" ::: "memory"); \
    __builtin_amdgcn_sched_barrier(0); \
    __builtin_amdgcn_s_setprio(1); \
    _Pragma("unroll") for (int ks = 0; ks < 2; ++ks) \
      _Pragma("unroll") for (int mf = 0; mf < 4; ++mf) \
        _Pragma("unroll") for (int nf = 0; nf < 2; ++nf) \
          acc[(QM_)*4 + mf][(QN_)*2 + nf] = __builtin_amdgcn_mfma_f32_16x16x32_bf16( \
              aR[mf][ks], bR[QN_][nf][ks], acc[(QM_)*4 + mf][(QN_)*2 + nf], 0, 0, 0); \
    __builtin_amdgcn_s_setprio(0); \
    TAIL_STMT; \
    __builtin_amdgcn_s_barrier(); \
} while (0)

    // prologue: full tiles kt=0 -> buf0, kt=1 -> buf1; gate buf0 only (8 left in flight)
    STAGE_A4(0, 0); STAGE_B4(0, 0);
    STAGE_A4(1, 1); STAGE_B4(1, 1);
    VM8;
    __builtin_amdgcn_s_barrier();

    for (int t = 0; t < NT_K / 2; ++t) {
        const int k2 = (2 * t + 2 < NT_K) ? 2 * t + 2 : NT_K - 1;
        const int k3 = (2 * t + 3 < NT_K) ? 2 * t + 3 : NT_K - 1;
        // buf0 = tile 2t, buf1 = tile 2t+1; stage next pair with 5-6 phase cover
        PH(0, 0, 0, 1, 1, PH_NOP,          PH_NOP);
        PH(0, 0, 1, 0, 1, PH_NOP,          PH_NOP);
        PH(0, 1, 0, 1, 0, STAGE_B4(0, k2), PH_NOP);   // buf0.B free after ph2
        PH(0, 1, 1, 0, 0, STAGE_A4(0, k2), VM8);      // buf0.A free after ph3; gate buf1 tiles
        PH(1, 0, 0, 1, 1, PH_NOP,          PH_NOP);
        PH(1, 0, 1, 0, 1, PH_NOP,          PH_NOP);
        PH(1, 1, 0, 1, 0, STAGE_B4(1, k3), PH_NOP);   // buf1.B free after ph6
        PH(1, 1, 1, 0, 0, STAGE_A4(1, k3), VM8);      // buf1.A free after ph7; gate k2 tiles
    }

    // ---- epilogue: scale per (e,col), f32 store, scatter by token id ----
    const int* toks = g_ids + base;
    float sc[4];
    #pragma unroll
    for (int nf = 0; nf < 4; ++nf)
        sc[nf] = scales[e * OUT_N + n0 + wn * 64 + nf * 16 + l15];
    #pragma unroll
    for (int mf = 0; mf < 8; ++mf) {
        #pragma unroll
        for (int r = 0; r < 4; ++r) {
            const int row = m0 + wm * 128 + mf * 16 + ((lane >> 4) << 2) + r;
            if (row >= cnt) continue;
            int tok = toks[row];
            if ((unsigned)tok >= (unsigned)T_N) continue;
            float* yrow = y + (long)tok * OUT_N;
            #pragma unroll
            for (int nf = 0; nf < 4; ++nf)
                yrow[n0 + wn * 64 + nf * 16 + l15] = acc[mf][nf][r] * sc[nf];
        }
    }
}

extern "C" void kernel_launch(void* const* d_in, const int* in_sizes, int n_in,
                              void* d_out, int out_size, void* d_ws, size_t ws_size,
                              hipStream_t stream) {
    const float* x      = nullptr;
    const int* indices  = nullptr;
    const int* qw       = nullptr;
    const void* meta    = nullptr;
    const float* scales = nullptr;
    int big_seen = 0;
    for (int i = 0; i < n_in; ++i) {
        long s = in_sizes[i];
        if (s == 33554432L)      x = (const float*)d_in[i];
        else if (s == 8192L)     indices = (const int*)d_in[i];
        else if (s == 32768L)    scales = (const float*)d_in[i];
        else if (s == 8388608L) {
            if (big_seen++ == 0)  qw = (const int*)d_in[i];
            else                  meta = d_in[i];
        }
    }
    if (!x || !indices || !qw || !meta || !scales) return;
    float* y = (float*)d_out;

    hipLaunchKernelGGL(sort_tokens, dim3(1), dim3(1024), 0, stream, indices, (const u16*)meta);
    hipLaunchKernelGGL(xb_convert, dim3(T_N), dim3(256), 0, stream, x);
    hipLaunchKernelGGL(decode_w, dim3(OUT_N / 256, 16, E_N), dim3(256), 0, stream, qw, meta);
    hipLaunchKernelGGL(moe_gemm, dim3(640), dim3(NTHREADS), 0, stream, scales, y);
}

// Round 9
// 698.583 us; speedup vs baseline: 1.0273x; 1.0273x over previous
//
#include <hip/hip_runtime.h>

#define E_N   8
#define IN_N  4096
#define OUT_N 4096
#define T_N   8192

#define BM 256
#define BN 256
#define NT_K 64            // number of 64-wide K-tiles
#define NTHREADS 512

typedef unsigned short u16;
typedef __bf16 bf16_t;
typedef bf16_t bf16x8 __attribute__((ext_vector_type(8)));
typedef u16    u16x8  __attribute__((ext_vector_type(8)));
typedef float  f32x4  __attribute__((ext_vector_type(4)));

// async global->LDS, 16B per lane (dest must be lane-linear: base + lane*16)
#define GLOAD16(gsrc, ldst) \
    __builtin_amdgcn_global_load_lds( \
        (const __attribute__((address_space(1))) unsigned int*)(gsrc), \
        (__attribute__((address_space(3))) unsigned int*)(ldst), 16, 0, 0)

// ---- device-global scratch (ws_size unknown -> module globals) ----
__device__ int g_cnt[E_N];
__device__ int g_base[E_N];
__device__ int g_ids[T_N];
__device__ int g_meta_wide;                            // 1 if meta widened int16->int32
// qw reshuffled: tap-contiguous per (e, g, o-group): dword at ((e*256+g)*512 + (o>>3))*8 + tap
__device__ int g_qwt[(long)E_N * 256 * 512 * 8];       // 33.5 MB
// meta transposed to k-major: u16 at (e*256+g)*4096 + o
__device__ u16 g_metat[(long)E_N * 256 * 4096];        // 16.8 MB
__device__ u16 g_xb[(long)T_N * IN_N];                 // 67 MB sorted bf16 tokens

__device__ __forceinline__ u16 f2bf(float f) {
    unsigned u = __builtin_bit_cast(unsigned, f);
    u += 0x7FFFu + ((u >> 16) & 1u);                   // round-to-nearest-even
    return (u16)(u >> 16);
}

// ---------------- kernel 1: bucket tokens by expert + meta-layout probe ----------------
__global__ void sort_tokens(const int* __restrict__ idx, const u16* __restrict__ meta16) {
    __shared__ int cnt[E_N], off[E_N];
    __shared__ int probe;
    const int tid = threadIdx.x;
    const int lane = tid & 63;
    if (tid == 0) probe = 0;
    if (tid < E_N) cnt[tid] = 0;
    __syncthreads();
    if (tid < 64) {
        unsigned v = meta16[2 * (tid * 131072) + 1];   // int32-widened meta -> odd u16 halves all 0
        if (v) atomicOr(&probe, 1);
    }
    for (int t0 = tid - lane; t0 < T_N; t0 += blockDim.x) {
        const int t = t0 + lane;
        const int my = idx[t] & 7;
        #pragma unroll
        for (int e = 0; e < E_N; ++e) {
            unsigned long long m = __ballot(my == e);
            if (lane == 0 && m) atomicAdd(&cnt[e], __popcll(m));
        }
    }
    __syncthreads();
    if (tid == 0) {
        int s = 0;
        for (int e = 0; e < E_N; ++e) { g_cnt[e] = cnt[e]; g_base[e] = s; off[e] = s; s += cnt[e]; }
        g_meta_wide = (probe == 0) ? 1 : 0;
    }
    __syncthreads();
    for (int t0 = tid - lane; t0 < T_N; t0 += blockDim.x) {
        const int t = t0 + lane;
        const int my = idx[t] & 7;
        #pragma unroll
        for (int e = 0; e < E_N; ++e) {
            unsigned long long m = __ballot(my == e);
            if (my == e) {
                int below = __popcll(m & ((1ull << lane) - 1ull));
                int basep = 0;
                if (below == 0) basep = atomicAdd(&off[e], __popcll(m));
                int src = __ffsll((long long)m) - 1;
                basep = __shfl(basep, src);
                int p = basep + below;
                if (p >= 0 && p < T_N) g_ids[p] = t;
            }
        }
    }
}

// ---------------- kernel 2: reshuffle qw -> tap-contiguous layout ----------------
__global__ __launch_bounds__(256, 4)
void qw_shuffle(const int* __restrict__ qw) {
    const int g = blockIdx.x;                          // 0..255
    const int e = blockIdx.y;
    const int* src = qw + (e * 128 + (g >> 1)) * 8192 + ((g & 1) << 12);
    int* dst = g_qwt + (long)(e * 256 + g) * 512 * 8;
    for (int og = threadIdx.x; og < 512; og += 256) {
        int q[8];
        #pragma unroll
        for (int t = 0; t < 8; ++t) q[t] = src[t * 512 + og];   // coalesced per t
        #pragma unroll
        for (int t = 0; t < 8; ++t) dst[og * 8 + t] = q[t];     // 32B contiguous per thread
    }
}

// ---------------- kernel 3: transpose meta -> k-major u16 ----------------
__global__ __launch_bounds__(256, 4)
void meta_transpose(const void* __restrict__ meta) {
    __shared__ u16 tile[16][272];
    const int e = blockIdx.z, g0 = blockIdx.y * 16, o0 = blockIdx.x * 256;
    const int o = o0 + threadIdx.x;
    if (g_meta_wide) {
        const int* mp = (const int*)meta + ((long)e * OUT_N + o) * 256 + g0;
        #pragma unroll
        for (int g = 0; g < 16; ++g) tile[g][threadIdx.x] = (u16)mp[g];
    } else {
        const u16* mp = (const u16*)meta + ((long)e * OUT_N + o) * 256 + g0;
        #pragma unroll
        for (int g = 0; g < 16; ++g) tile[g][threadIdx.x] = mp[g];
    }
    __syncthreads();
    #pragma unroll
    for (int g = 0; g < 16; ++g)
        g_metat[(long)(e * 256 + g0 + g) * 4096 + o0 + threadIdx.x] = tile[g][threadIdx.x];
}

// ---------------- kernel 4: gather + convert x (f32) -> sorted bf16 rows ----------------
__global__ __launch_bounds__(256, 4)
void xb_convert(const float* __restrict__ x) {
    const int p = blockIdx.x;
    int tok = g_ids[p];
    if ((unsigned)tok >= (unsigned)T_N) tok = 0;
    const float* src = x + (long)tok * IN_N;
    u16* dst = g_xb + (long)p * IN_N;
    const int tid = threadIdx.x;
    float va[16];
    #pragma unroll
    for (int c4 = 0; c4 < 4; ++c4) {
        float4 v = *reinterpret_cast<const float4*>(src + tid * 16 + c4 * 4);
        va[c4 * 4 + 0] = v.x; va[c4 * 4 + 1] = v.y; va[c4 * 4 + 2] = v.z; va[c4 * 4 + 3] = v.w;
    }
    unsigned wp[8];
    #pragma unroll
    for (int p8 = 0; p8 < 8; ++p8)
        wp[p8] = (unsigned)f2bf(va[2 * p8]) | ((unsigned)f2bf(va[2 * p8 + 1]) << 16);
    *reinterpret_cast<int4*>(dst + tid * 16)     = make_int4((int)wp[0], (int)wp[1], (int)wp[2], (int)wp[3]);
    *reinterpret_cast<int4*>(dst + tid * 16 + 8) = make_int4((int)wp[4], (int)wp[5], (int)wp[6], (int)wp[7]);
}

// ---------------- kernel 5: grouped bf16 GEMM, 8-phase, FUSED 2:4 decode for B ----------------
__global__ __launch_bounds__(NTHREADS, 2)
void moe_gemm(const float* __restrict__ scales, float* __restrict__ y) {
    const int e = blockIdx.z;
    int cnt = g_cnt[e];
    if (cnt < 0) cnt = 0;
    if (cnt > T_N) cnt = T_N;
    const int m0 = blockIdx.y * BM;
    if (m0 >= cnt) return;
    const int n0 = blockIdx.x * BN;
    int base = g_base[e];
    if (base < 0) base = 0;
    if (base > T_N - cnt) base = T_N - cnt;

    __shared__ __align__(16) u16 As[2 * BM * 64];   // 64 KiB, swizzled image
    __shared__ __align__(16) u16 Bs[2 * BN * 64];   // 64 KiB, swizzled image (rows = out-cols)

    const int tid  = threadIdx.x;
    const int lane = tid & 63;
    const int wid  = tid >> 6;
    const int wm   = wid >> 2;     // 0..1
    const int wn   = wid & 3;      // 0..3

    // ---- A staging (gload_lds, pre-swizzled global source, linear LDS dest) ----
    const int r_loc = tid >> 3;
    const int h_a   = (tid & 7) ^ (r_loc & 7);
    const u16* asrc[4];
    #pragma unroll
    for (int q = 0; q < 4; ++q) {
        long grow = (long)base + m0 + q * 64 + r_loc;
        if (grow > T_N - 1) grow = T_N - 1;        // tail rows: dup data, masked at store
        asrc[q] = g_xb + grow * IN_N + h_a * 8;
    }
#define STAGE_A4(B_, KT_) do { \
    GLOAD16(asrc[0] + (KT_) * 64, &As[(B_)*16384 + tid * 8]); \
    GLOAD16(asrc[1] + (KT_) * 64, &As[(B_)*16384 + (512 + tid) * 8]); \
    GLOAD16(asrc[2] + (KT_) * 64, &As[(B_)*16384 + (1024 + tid) * 8]); \
    GLOAD16(asrc[3] + (KT_) * 64, &As[(B_)*16384 + (1536 + tid) * 8]); \
} while (0)

    // ---- B fused decode: thread owns col cB, items gi = {giA, giB} per K-tile ----
    const int cB  = tid & 255;
    const int giA = tid >> 8;          // 0..1
    const int giB = 2 + (tid >> 8);    // 2..3
    const int ogB = (n0 + cB) >> 3;
    const unsigned shB = (cB & 7) << 2;
    int4 qA0, qA1, qB0, qB1;
    unsigned mwA, mwB;

#define LOADB(Q0_, Q1_, MW_, GI_, KT_) do { \
    const int g_ = (KT_) * 4 + (GI_); \
    const int4* qt_ = (const int4*)(g_qwt + ((long)(e * 256 + g_) * 512 + ogB) * 8); \
    Q0_ = qt_[0]; Q1_ = qt_[1]; \
    MW_ = g_metat[(long)(e * 256 + g_) * 4096 + n0 + cB]; \
} while (0)

#define DECB(Q0_, Q1_, MW_, GI_, B_) do { \
    const unsigned qv_[8] = { (unsigned)(Q0_).x, (unsigned)(Q0_).y, (unsigned)(Q0_).z, (unsigned)(Q0_).w, \
                              (unsigned)(Q1_).x, (unsigned)(Q1_).y, (unsigned)(Q1_).z, (unsigned)(Q1_).w }; \
    int d_[16]; \
    _Pragma("unroll") for (int p = 0; p < 16; ++p) d_[p] = 0; \
    _Pragma("unroll") for (int grp = 0; grp < 4; ++grp) { \
        const int v0_ = (int)((qv_[2 * grp]     >> shB) & 0xF) - 8; \
        const int v1_ = (int)((qv_[2 * grp + 1] >> shB) & 0xF) - 8; \
        const int s0_ = ((MW_) >> (4 * grp)) & 3; \
        const int s1_ = ((MW_) >> (4 * grp + 2)) & 3; \
        _Pragma("unroll") for (int qq = 0; qq < 4; ++qq) { \
            int t0_ = (s0_ == qq) ? v0_ : 0; \
            int t1_ = (s1_ == qq) ? v1_ : 0; \
            d_[grp * 4 + qq] = t0_ + t1_;          /* collisions sum, matching .at[].add */ \
        } \
    } \
    unsigned wp_[8]; \
    _Pragma("unroll") for (int p = 0; p < 8; ++p) { \
        unsigned lo_ = __builtin_bit_cast(unsigned, (float)d_[2 * p])     >> 16;  /* exact, |d|<=16 */ \
        unsigned hi_ = __builtin_bit_cast(unsigned, (float)d_[2 * p + 1]) >> 16; \
        wp_[p] = lo_ | (hi_ << 16); \
    } \
    *reinterpret_cast<int4*>(&Bs[(B_)*16384 + (cB * 8 + ((2 * (GI_) + 0) ^ (cB & 7))) * 8]) = \
        make_int4((int)wp_[0], (int)wp_[1], (int)wp_[2], (int)wp_[3]); \
    *reinterpret_cast<int4*>(&Bs[(B_)*16384 + (cB * 8 + ((2 * (GI_) + 1) ^ (cB & 7))) * 8]) = \
        make_int4((int)wp_[4], (int)wp_[5], (int)wp_[6], (int)wp_[7]); \
} while (0)

    // ---- MFMA-read precompute ----
    const int l15   = lane & 15;
    const int aoff0 = ((((lane >> 4))     ^ (lane & 7)) << 3);   // ks=0
    const int aoff1 = (((4 + (lane >> 4)) ^ (lane & 7)) << 3);   // ks=1
    const int arow0 = (wm * 128 + l15) * 64;
    const int brow0 = (wn * 64  + l15) * 64;

#define LD8(P_) __builtin_bit_cast(bf16x8, *reinterpret_cast<const u16x8*>(P_))
#define VM4 asm volatile("s_waitcnt vmcnt(4)" ::: "memory")
#define PH_NOP ((void)0)

    f32x4 acc[8][4];
    #pragma unroll
    for (int i = 0; i < 8; ++i)
        #pragma unroll
        for (int j = 0; j < 4; ++j) acc[i][j] = (f32x4){0.f, 0.f, 0.f, 0.f};

    bf16x8 aR[4][2];
    bf16x8 bR[2][2][2];

#define PH(B_, QM_, QN_, RDA_, RDB_, STAGE_STMT, TAIL_STMT) do { \
    if (RDA_) { _Pragma("unroll") for (int mf = 0; mf < 4; ++mf) { \
        const u16* p_ = &As[(B_)*16384 + arow0 + (QM_)*4096 + mf*1024]; \
        aR[mf][0] = LD8(p_ + aoff0); aR[mf][1] = LD8(p_ + aoff1); } } \
    if (RDB_) { _Pragma("unroll") for (int nf = 0; nf < 2; ++nf) { \
        const u16* p_ = &Bs[(B_)*16384 + brow0 + (QN_)*2048 + nf*1024]; \
        bR[QN_][nf][0] = LD8(p_ + aoff0); bR[QN_][nf][1] = LD8(p_ + aoff1); } } \
    STAGE_STMT; \
    __builtin_amdgcn_s_barrier(); \
    asm volatile("s_waitcnt lgkmcnt(0)" ::: "memory"); \
    __builtin_amdgcn_sched_barrier(0); \
    __builtin_amdgcn_s_setprio(1); \
    _Pragma("unroll") for (int ks = 0; ks < 2; ++ks) \
      _Pragma("unroll") for (int mf = 0; mf < 4; ++mf) \
        _Pragma("unroll") for (int nf = 0; nf < 2; ++nf) \
          acc[(QM_)*4 + mf][(QN_)*2 + nf] = __builtin_amdgcn_mfma_f32_16x16x32_bf16( \
              aR[mf][ks], bR[QN_][nf][ks], acc[(QM_)*4 + mf][(QN_)*2 + nf], 0, 0, 0); \
    __builtin_amdgcn_s_setprio(0); \
    TAIL_STMT; \
    __builtin_amdgcn_s_barrier(); \
} while (0)

    // prologue: A tiles 0,1 via gload_lds; B tiles 0,1 decoded directly
    STAGE_A4(0, 0); STAGE_A4(1, 1);
    LOADB(qA0, qA1, mwA, giA, 0); LOADB(qB0, qB1, mwB, giB, 0);
    DECB(qA0, qA1, mwA, giA, 0);  DECB(qB0, qB1, mwB, giB, 0);
    LOADB(qA0, qA1, mwA, giA, 1); LOADB(qB0, qB1, mwB, giB, 1);
    DECB(qA0, qA1, mwA, giA, 1);  DECB(qB0, qB1, mwB, giB, 1);
    asm volatile("s_waitcnt lgkmcnt(0)" ::: "memory");   // drain own ds_writes pre-barrier
    asm volatile("s_waitcnt vmcnt(4)" ::: "memory");     // A(0) done; A(1) still in flight
    __builtin_amdgcn_s_barrier();

    for (int t = 0; t < NT_K / 2; ++t) {
        const int k2 = (2 * t + 2 < NT_K) ? 2 * t + 2 : NT_K - 1;
        const int k3 = (2 * t + 3 < NT_K) ? 2 * t + 3 : NT_K - 1;
        // buf0 = tile 2t, buf1 = 2t+1. B-decode k2->buf0 (B region free after ph2),
        // A gload k2->buf0 after ph3; same pattern for buf1 at ph5-8.
        PH(0, 0, 0, 1, 1, LOADB(qA0, qA1, mwA, giA, k2), PH_NOP);
        PH(0, 0, 1, 0, 1, LOADB(qB0, qB1, mwB, giB, k2), PH_NOP);
        PH(0, 1, 0, 1, 0, DECB(qA0, qA1, mwA, giA, 0),   PH_NOP);
        PH(0, 1, 1, 0, 0, DECB(qB0, qB1, mwB, giB, 0); STAGE_A4(0, k2), VM4);
        PH(1, 0, 0, 1, 1, LOADB(qA0, qA1, mwA, giA, k3), PH_NOP);
        PH(1, 0, 1, 0, 1, LOADB(qB0, qB1, mwB, giB, k3), PH_NOP);
        PH(1, 1, 0, 1, 0, DECB(qA0, qA1, mwA, giA, 1),   PH_NOP);
        PH(1, 1, 1, 0, 0, DECB(qB0, qB1, mwB, giB, 1); STAGE_A4(1, k3), VM4);
    }

    // ---- epilogue: scale per (e,col), f32 store, scatter by token id ----
    const int* toks = g_ids + base;
    float sc[4];
    #pragma unroll
    for (int nf = 0; nf < 4; ++nf)
        sc[nf] = scales[e * OUT_N + n0 + wn * 64 + nf * 16 + l15];
    #pragma unroll
    for (int mf = 0; mf < 8; ++mf) {
        #pragma unroll
        for (int r = 0; r < 4; ++r) {
            const int row = m0 + wm * 128 + mf * 16 + ((lane >> 4) << 2) + r;
            if (row >= cnt) continue;
            int tok = toks[row];
            if ((unsigned)tok >= (unsigned)T_N) continue;
            float* yrow = y + (long)tok * OUT_N;
            #pragma unroll
            for (int nf = 0; nf < 4; ++nf)
                yrow[n0 + wn * 64 + nf * 16 + l15] = acc[mf][nf][r] * sc[nf];
        }
    }
}

extern "C" void kernel_launch(void* const* d_in, const int* in_sizes, int n_in,
                              void* d_out, int out_size, void* d_ws, size_t ws_size,
                              hipStream_t stream) {
    const float* x      = nullptr;
    const int* indices  = nullptr;
    const int* qw       = nullptr;
    const void* meta    = nullptr;
    const float* scales = nullptr;
    int big_seen = 0;
    for (int i = 0; i < n_in; ++i) {
        long s = in_sizes[i];
        if (s == 33554432L)      x = (const float*)d_in[i];
        else if (s == 8192L)     indices = (const int*)d_in[i];
        else if (s == 32768L)    scales = (const float*)d_in[i];
        else if (s == 8388608L) {
            if (big_seen++ == 0)  qw = (const int*)d_in[i];
            else                  meta = d_in[i];
        }
    }
    if (!x || !indices || !qw || !meta || !scales) return;
    float* y = (float*)d_out;

    hipLaunchKernelGGL(sort_tokens, dim3(1), dim3(1024), 0, stream, indices, (const u16*)meta);
    hipLaunchKernelGGL(qw_shuffle, dim3(256, E_N), dim3(256), 0, stream, qw);
    hipLaunchKernelGGL(meta_transpose, dim3(16, 16, E_N), dim3(256), 0, stream, meta);
    hipLaunchKernelGGL(xb_convert, dim3(T_N), dim3(256), 0, stream, x);
    hipLaunchKernelGGL(moe_gemm, dim3(OUT_N / BN, T_N / BM, E_N), dim3(NTHREADS), 0, stream, scales, y);
}

// Round 10
// 648.436 us; speedup vs baseline: 1.1068x; 1.0773x over previous
//
#include <hip/hip_runtime.h>

#define E_N   8
#define IN_N  4096
#define OUT_N 4096
#define T_N   8192

#define BM 256
#define BN 256
#define NT_K 64            // number of 64-wide K-tiles
#define NTHREADS 512

typedef unsigned short u16;
typedef __bf16 bf16_t;
typedef bf16_t bf16x8 __attribute__((ext_vector_type(8)));
typedef u16    u16x8  __attribute__((ext_vector_type(8)));
typedef float  f32x4  __attribute__((ext_vector_type(4)));

// async global->LDS, 16B per lane (dest must be lane-linear: base + lane*16)
#define GLOAD16(gsrc, ldst) \
    __builtin_amdgcn_global_load_lds( \
        (const __attribute__((address_space(1))) unsigned int*)(gsrc), \
        (__attribute__((address_space(3))) unsigned int*)(ldst), 16, 0, 0)

// ---- device-global scratch (ws_size unknown -> module globals) ----
__device__ int g_cnt[E_N];
__device__ int g_base[E_N];
__device__ int g_ids[T_N];
__device__ int g_meta_wide;                       // 1 if meta widened int16->int32
// W stored as the LDS-image of each (e,kt) slab [256 rows][8 chunks of 16B],
// chunk h of row o at chunk index o*8 + (h ^ (o&7))  (T2 swizzle).
__device__ u16 g_W[(long)E_N * OUT_N * IN_N];     // 268 MB dense bf16
__device__ u16 g_xb[(long)T_N * IN_N];            // 67 MB sorted bf16 tokens

__device__ __forceinline__ u16 f2bf(float f) {
    unsigned u = __builtin_bit_cast(unsigned, f);
    u += 0x7FFFu + ((u >> 16) & 1u);              // round-to-nearest-even
    return (u16)(u >> 16);
}

// ---------------- kernel 1: bucket tokens by expert + meta-layout probe ----------------
__global__ void sort_tokens(const int* __restrict__ idx, const u16* __restrict__ meta16) {
    __shared__ int cnt[E_N], off[E_N];
    __shared__ int probe;
    const int tid = threadIdx.x;
    const int lane = tid & 63;
    if (tid == 0) probe = 0;
    if (tid < E_N) cnt[tid] = 0;
    __syncthreads();
    if (tid < 64) {
        unsigned v = meta16[2 * (tid * 131072) + 1];   // int32-widened meta -> odd u16 halves all 0
        if (v) atomicOr(&probe, 1);
    }
    for (int t0 = tid - lane; t0 < T_N; t0 += blockDim.x) {
        const int t = t0 + lane;
        const int my = idx[t] & 7;
        #pragma unroll
        for (int e = 0; e < E_N; ++e) {
            unsigned long long m = __ballot(my == e);
            if (lane == 0 && m) atomicAdd(&cnt[e], __popcll(m));
        }
    }
    __syncthreads();
    if (tid == 0) {
        int s = 0;
        for (int e = 0; e < E_N; ++e) { g_cnt[e] = cnt[e]; g_base[e] = s; off[e] = s; s += cnt[e]; }
        g_meta_wide = (probe == 0) ? 1 : 0;
    }
    __syncthreads();
    for (int t0 = tid - lane; t0 < T_N; t0 += blockDim.x) {
        const int t = t0 + lane;
        const int my = idx[t] & 7;
        #pragma unroll
        for (int e = 0; e < E_N; ++e) {
            unsigned long long m = __ballot(my == e);
            if (my == e) {
                int below = __popcll(m & ((1ull << lane) - 1ull));
                int basep = 0;
                if (below == 0) basep = atomicAdd(&off[e], __popcll(m));
                int src = __ffsll((long long)m) - 1;
                basep = __shfl(basep, src);
                int p = basep + below;
                if (p >= 0 && p < T_N) g_ids[p] = t;
            }
        }
    }
}

// ---------------- kernel 2: FUSED prep — decode_w (blocks 0..2047) + xb_convert (2048..10239) ----------------
__global__ __launch_bounds__(256, 4)
void prep(const float* __restrict__ x, const int* __restrict__ qw, const void* __restrict__ meta) {
    const int b = blockIdx.x;
    if (b < 2048) {
        // ---- decode 2:4 int4 -> dense bf16 W, swizzled k-tiled layout ----
        const int e   = b >> 8;
        const int kt0 = ((b >> 4) & 15) * 4;          // 4 k-tiles of 64 -> 16 g-blocks
        const int o   = (b & 15) * 256 + threadIdx.x;
        const bool mwide = (g_meta_wide != 0);
        unsigned mws[16];
        if (mwide) {
            const int* mp = (const int*)meta + ((long)e * OUT_N + o) * (IN_N / 16) + kt0 * 4;
            #pragma unroll
            for (int i = 0; i < 16; ++i) mws[i] = (unsigned)mp[i] & 0xFFFFu;
        } else {
            const u16* mp = (const u16*)meta + ((long)e * OUT_N + o) * (IN_N / 16) + kt0 * 4;
            #pragma unroll
            for (int i = 0; i < 16; ++i) mws[i] = mp[i];
        }
        const unsigned sh = (o & 7) << 2;
        const int osw = o & 7;
        #pragma unroll
        for (int ki = 0; ki < 4; ++ki) {
            const int kt = kt0 + ki;
            unsigned wp[32];
            #pragma unroll
            for (int gi = 0; gi < 4; ++gi) {
                const int g = kt * 4 + gi;
                const unsigned mw = mws[ki * 4 + gi];
                const int* qp = qw + ((e * (IN_N / 32) + (g >> 1)) << 13) + (o >> 3) + ((g & 1) << 12);
                int d[16];
                #pragma unroll
                for (int p = 0; p < 16; ++p) d[p] = 0;
                #pragma unroll
                for (int grp = 0; grp < 4; ++grp) {
                    const unsigned w0 = (unsigned)qp[(2 * grp) * 512];
                    const unsigned w1 = (unsigned)qp[(2 * grp + 1) * 512];
                    const int v0 = (int)((w0 >> sh) & 0xF) - 8;
                    const int v1 = (int)((w1 >> sh) & 0xF) - 8;
                    const int s0 = (mw >> (4 * grp)) & 3;
                    const int s1 = (mw >> (4 * grp + 2)) & 3;
                    #pragma unroll
                    for (int q = 0; q < 4; ++q) {
                        int t0 = (s0 == q) ? v0 : 0;
                        int t1 = (s1 == q) ? v1 : 0;
                        d[grp * 4 + q] = t0 + t1;     // collisions sum, matching .at[].add
                    }
                }
                #pragma unroll
                for (int p = 0; p < 8; ++p) {
                    unsigned lo = __builtin_bit_cast(unsigned, (float)d[2 * p])     >> 16;  // exact, |d|<=30
                    unsigned hi = __builtin_bit_cast(unsigned, (float)d[2 * p + 1]) >> 16;
                    wp[gi * 8 + p] = lo | (hi << 16);
                }
            }
            u16* wr = g_W + ((long)(e * 64 + kt) * OUT_N + o) * 64;
            #pragma unroll
            for (int h = 0; h < 8; ++h)
                *reinterpret_cast<int4*>(wr + (h ^ osw) * 8) =
                    make_int4((int)wp[h * 4], (int)wp[h * 4 + 1], (int)wp[h * 4 + 2], (int)wp[h * 4 + 3]);
        }
    } else {
        // ---- gather + convert x (f32) -> sorted bf16 rows ----
        const int p = b - 2048;
        int tok = g_ids[p];
        if ((unsigned)tok >= (unsigned)T_N) tok = 0;
        const float* src = x + (long)tok * IN_N;
        u16* dst = g_xb + (long)p * IN_N;
        const int tid = threadIdx.x;
        float va[16];
        #pragma unroll
        for (int c4 = 0; c4 < 4; ++c4) {
            float4 v = *reinterpret_cast<const float4*>(src + tid * 16 + c4 * 4);
            va[c4 * 4 + 0] = v.x; va[c4 * 4 + 1] = v.y; va[c4 * 4 + 2] = v.z; va[c4 * 4 + 3] = v.w;
        }
        unsigned wp[8];
        #pragma unroll
        for (int p8 = 0; p8 < 8; ++p8)
            wp[p8] = (unsigned)f2bf(va[2 * p8]) | ((unsigned)f2bf(va[2 * p8 + 1]) << 16);
        *reinterpret_cast<int4*>(dst + tid * 16)     = make_int4((int)wp[0], (int)wp[1], (int)wp[2], (int)wp[3]);
        *reinterpret_cast<int4*>(dst + tid * 16 + 8) = make_int4((int)wp[4], (int)wp[5], (int)wp[6], (int)wp[7]);
    }
}

// ---------------- kernel 3: grouped bf16 GEMM, 256x256 8-phase (verified 430 us version) ----------------
__global__ __launch_bounds__(NTHREADS, 2)
void moe_gemm(const float* __restrict__ scales, float* __restrict__ y) {
    const int e = blockIdx.z;
    int cnt = g_cnt[e];
    if (cnt < 0) cnt = 0;
    if (cnt > T_N) cnt = T_N;
    const int m0 = blockIdx.y * BM;
    if (m0 >= cnt) return;
    const int n0 = blockIdx.x * BN;
    int base = g_base[e];
    if (base < 0) base = 0;
    if (base > T_N - cnt) base = T_N - cnt;

    __shared__ __align__(16) u16 As[2 * BM * 64];   // 64 KiB, swizzled image
    __shared__ __align__(16) u16 Bs[2 * BN * 64];   // 64 KiB

    const int tid  = threadIdx.x;
    const int lane = tid & 63;
    const int wid  = tid >> 6;
    const int wm   = wid >> 2;     // 0..1
    const int wn   = wid & 3;      // 0..3

    // ---- staging precompute (per-lane swizzled global source, linear LDS dest) ----
    const int r_loc = tid >> 3;
    const int h_a   = (tid & 7) ^ (r_loc & 7);
    const u16* asrc[4];
    #pragma unroll
    for (int q = 0; q < 4; ++q) {                  // q = ht*2 + j : row = m0 + q*64 + r_loc
        long grow = (long)base + m0 + q * 64 + r_loc;
        if (grow > T_N - 1) grow = T_N - 1;        // tail rows: dup data, masked at store
        asrc[q] = g_xb + grow * IN_N + h_a * 8;
    }
    const u16* bsrc = g_W + ((long)e * NT_K * OUT_N + n0) * 64 + (long)tid * 8;

#define STAGE_A(B_, KT_, HT_) do { \
    const int ktc_ = ((KT_) < NT_K) ? (KT_) : (NT_K - 1); \
    GLOAD16(asrc[(HT_)*2 + 0] + ktc_ * 64, &As[(B_)*16384 + ((HT_)*1024 + tid) * 8]); \
    GLOAD16(asrc[(HT_)*2 + 1] + ktc_ * 64, &As[(B_)*16384 + ((HT_)*1024 + 512 + tid) * 8]); \
} while (0)
#define STAGE_B(B_, KT_, HT_) do { \
    const int ktc_ = ((KT_) < NT_K) ? (KT_) : (NT_K - 1); \
    const u16* s_ = bsrc + (long)ktc_ * (OUT_N * 64) + (HT_) * 8192; \
    GLOAD16(s_,        &Bs[(B_)*16384 + ((HT_)*1024 + tid) * 8]); \
    GLOAD16(s_ + 4096, &Bs[(B_)*16384 + ((HT_)*1024 + 512 + tid) * 8]); \
} while (0)

    // ---- MFMA-read precompute ----
    const int l15   = lane & 15;
    const int aoff0 = ((((lane >> 4))     ^ (lane & 7)) << 3);   // ks=0: h = lane>>4
    const int aoff1 = (((4 + (lane >> 4)) ^ (lane & 7)) << 3);   // ks=1: h = 4 + lane>>4
    const int arow0 = (wm * 128 + l15) * 64;
    const int brow0 = (wn * 64  + l15) * 64;

#define LD8(P_) __builtin_bit_cast(bf16x8, *reinterpret_cast<const u16x8*>(P_))
#define VM4 asm volatile("s_waitcnt vmcnt(4)" ::: "memory")
#define PH_NOP ((void)0)

    f32x4 acc[8][4];
    #pragma unroll
    for (int i = 0; i < 8; ++i)
        #pragma unroll
        for (int j = 0; j < 4; ++j) acc[i][j] = (f32x4){0.f, 0.f, 0.f, 0.f};

    bf16x8 aR[4][2];       // A frags for current qm (reused across 2 phases)
    bf16x8 bR[2][2][2];    // B frags for BOTH qn (B LDS region free after phase 2)

// one phase: {ds_read subtile | stage 1 half-tile | barrier | lgkmcnt(0) | setprio(1) 16xMFMA setprio(0) | tail | barrier}
#define PH(B_, QM_, QN_, RDA_, RDB_, STAGE_STMT, TAIL_STMT) do { \
    if (RDA_) { _Pragma("unroll") for (int mf = 0; mf < 4; ++mf) { \
        const u16* p_ = &As[(B_)*16384 + arow0 + (QM_)*4096 + mf*1024]; \
        aR[mf][0] = LD8(p_ + aoff0); aR[mf][1] = LD8(p_ + aoff1); } } \
    if (RDB_) { _Pragma("unroll") for (int nf = 0; nf < 2; ++nf) { \
        const u16* p_ = &Bs[(B_)*16384 + brow0 + (QN_)*2048 + nf*1024]; \
        bR[QN_][nf][0] = LD8(p_ + aoff0); bR[QN_][nf][1] = LD8(p_ + aoff1); } } \
    STAGE_STMT; \
    __builtin_amdgcn_s_barrier(); \
    asm volatile("s_waitcnt lgkmcnt(0)" ::: "memory"); \
    __builtin_amdgcn_sched_barrier(0); \
    __builtin_amdgcn_s_setprio(1); \
    _Pragma("unroll") for (int ks = 0; ks < 2; ++ks) \
      _Pragma("unroll") for (int mf = 0; mf < 4; ++mf) \
        _Pragma("unroll") for (int nf = 0; nf < 2; ++nf) \
          acc[(QM_)*4 + mf][(QN_)*2 + nf] = __builtin_amdgcn_mfma_f32_16x16x32_bf16( \
              aR[mf][ks], bR[QN_][nf][ks], acc[(QM_)*4 + mf][(QN_)*2 + nf], 0, 0, 0); \
    __builtin_amdgcn_s_setprio(0); \
    TAIL_STMT; \
    __builtin_amdgcn_s_barrier(); \
} while (0)

    // prologue: A(0),B(0) -> buf0; B(1) -> buf1; allow B(1) in flight
    STAGE_A(0, 0, 0); STAGE_A(0, 0, 1);
    STAGE_B(0, 0, 0); STAGE_B(0, 0, 1);
    STAGE_B(1, 1, 0); STAGE_B(1, 1, 1);
    VM4;
    __builtin_amdgcn_s_barrier();

    for (int t = 0; t < NT_K / 2; ++t) {
        const int k1 = 2 * t + 1, k2 = 2 * t + 2, k3 = 2 * t + 3;
        PH(0, 0, 0, 1, 1, STAGE_A(1, k1, 0), PH_NOP);   // buf1 A free since prev ph7
        PH(0, 0, 1, 0, 1, STAGE_A(1, k1, 1), PH_NOP);
        PH(0, 1, 0, 1, 0, STAGE_B(0, k2, 0), PH_NOP);   // buf0 B free after ph2
        PH(0, 1, 1, 0, 0, STAGE_B(0, k2, 1), VM4);      // A(k1) landed before ph5
        PH(1, 0, 0, 1, 1, STAGE_A(0, k2, 0), PH_NOP);   // buf0 A free after ph3
        PH(1, 0, 1, 0, 1, STAGE_A(0, k2, 1), PH_NOP);
        PH(1, 1, 0, 1, 0, STAGE_B(1, k3, 0), PH_NOP);   // buf1 B free after ph6
        PH(1, 1, 1, 0, 0, STAGE_B(1, k3, 1), VM4);      // A(k2),B(k2) landed before next ph1
    }

    // ---- epilogue: scale per (e,col), f32 store, scatter by token id ----
    const int* toks = g_ids + base;
    float sc[4];
    #pragma unroll
    for (int nf = 0; nf < 4; ++nf)
        sc[nf] = scales[e * OUT_N + n0 + wn * 64 + nf * 16 + l15];
    #pragma unroll
    for (int mf = 0; mf < 8; ++mf) {
        #pragma unroll
        for (int r = 0; r < 4; ++r) {
            const int row = m0 + wm * 128 + mf * 16 + ((lane >> 4) << 2) + r;
            if (row >= cnt) continue;
            int tok = toks[row];
            if ((unsigned)tok >= (unsigned)T_N) continue;
            float* yrow = y + (long)tok * OUT_N;
            #pragma unroll
            for (int nf = 0; nf < 4; ++nf)
                yrow[n0 + wn * 64 + nf * 16 + l15] = acc[mf][nf][r] * sc[nf];
        }
    }
}

extern "C" void kernel_launch(void* const* d_in, const int* in_sizes, int n_in,
                              void* d_out, int out_size, void* d_ws, size_t ws_size,
                              hipStream_t stream) {
    const float* x      = nullptr;
    const int* indices  = nullptr;
    const int* qw       = nullptr;
    const void* meta    = nullptr;
    const float* scales = nullptr;
    int big_seen = 0;
    for (int i = 0; i < n_in; ++i) {
        long s = in_sizes[i];
        if (s == 33554432L)      x = (const float*)d_in[i];
        else if (s == 8192L)     indices = (const int*)d_in[i];
        else if (s == 32768L)    scales = (const float*)d_in[i];
        else if (s == 8388608L) {
            if (big_seen++ == 0)  qw = (const int*)d_in[i];
            else                  meta = d_in[i];
        }
    }
    if (!x || !indices || !qw || !meta || !scales) return;
    float* y = (float*)d_out;

    hipLaunchKernelGGL(sort_tokens, dim3(1), dim3(1024), 0, stream, indices, (const u16*)meta);
    hipLaunchKernelGGL(prep, dim3(10240), dim3(256), 0, stream, x, qw, meta);
    hipLaunchKernelGGL(moe_gemm, dim3(OUT_N / BN, T_N / BM, E_N), dim3(NTHREADS), 0, stream, scales, y);
}